// Round 13
// baseline (157.967 us; speedup 1.0000x reference)
//
#include <hip/hip_runtime.h>

// ---------------------------------------------------------------------------
// StateBank R13: scan commutes with M_k (decay scalar per k):
//   zeta_k = scan_pk(u)  (chunked: carries=vpart -> incomings -> apply)
//   g = b_out + [M_0..M_3] @ [zeta_0..zeta_3]  (K=4096 GEMM, epilogue adds
//       p^{t+1} z0 + ct(1-p^{t+1}) terms and writes f32 g directly)
//   s_last = p^T s0 + W_in_k @ vfull_k + b_in geom   (unchanged)
// Deletes: Y materialization (64MB wr + 64MB rd), scanB pass, U_bf.
// gemm_big: R11-frozen K-loop (128^2, 4 waves, BK=32, conflict-free XOR,
// counted vmcnt), now K=4096 (128 iters), grid 512 (64Mx8N tiles).
// ---------------------------------------------------------------------------

#define Bb 4
#define Tt 2048
#define Dd 1024
#define Kk 4
#define BT (Bb*Tt)          // 8192
#define Ee (Kk*Dd)          // 4096
#define NCH 32              // scan chunks
#define LCH 64              // chunk length (NCH*LCH = T)

typedef __bf16 bf16x8 __attribute__((ext_vector_type(8)));
typedef float  f32x4  __attribute__((ext_vector_type(4)));

__device__ __forceinline__ float bf2f(ushort u){
  union { unsigned int i; float f; } x; x.i = ((unsigned int)u) << 16; return x.f;
}
__device__ __forceinline__ ushort f2bf(float f){
  union { unsigned int i; float f; } x; x.f = f;
  unsigned int i = x.i;
  return (ushort)((i + 0x7FFFu + ((i >> 16) & 1u)) >> 16);   // RNE
}
__device__ __forceinline__ float sigm(float x){ return 1.0f / (1.0f + expf(-x)); }

// ---------------- fused prep: u-carries | W_in transpose | W_out pass -------
// grid 1D x 256 threads:
//   [0,128)     : u -> vpart (zeta chunk carries; 4 d per thread, float4)
//   [128,4224)  : W_in (4096x1024 f32) -> WinT (1024x4096 bf16)
//   [4224,5248) : W_out -> Wout_bf + z0 + cterm (wave per (k,d) row)
__global__ __launch_bounds__(256) void k_prep_all(
    const float* __restrict__ u, const float* __restrict__ dlog,
    float* __restrict__ vpart,
    const float* __restrict__ W_in, ushort* __restrict__ WinT,
    const float* __restrict__ Wout, const float* __restrict__ s0,
    const float* __restrict__ b_in, ushort* __restrict__ Wout_bf,
    float* __restrict__ z0, float* __restrict__ cterm){
  const int bid = blockIdx.x;
  const int tid = threadIdx.x;

  if (bid < 128){
    int x = bid, c = x & 31, b = x >> 5;
    int d0 = tid * 4;
    float p[4];
    #pragma unroll
    for (int k = 0; k < 4; ++k) p[k] = sigm(dlog[k]);
    f32x4 a0 = {0,0,0,0}, a1 = {0,0,0,0}, a2 = {0,0,0,0}, a3 = {0,0,0,0};
    size_t ub = ((size_t)(b*Tt + c*LCH)) * Dd + d0;
    for (int i = 0; i < LCH; ++i){
      f32x4 uv = *(const f32x4*)(u + ub);
      a0 = p[0]*a0 + uv; a1 = p[1]*a1 + uv; a2 = p[2]*a2 + uv; a3 = p[3]*a3 + uv;
      ub += Dd;
    }
    size_t vb = ((size_t)x * Kk) * Dd + d0;
    *(f32x4*)(vpart + vb)          = a0;
    *(f32x4*)(vpart + vb + Dd)     = a1;
    *(f32x4*)(vpart + vb + 2*Dd)   = a2;
    *(f32x4*)(vpart + vb + 3*Dd)   = a3;
  } else if (bid < 4224){
    __shared__ float tile[32][33];
    int bb = bid - 128;
    int c0 = (bb & 31) * 32, r0 = (bb >> 5) * 32;
    int tx = tid & 31, ty = tid >> 5;     // 32 x 8
    #pragma unroll
    for (int j = 0; j < 4; ++j)
      tile[ty + j*8][tx] = W_in[(size_t)(r0 + ty + j*8) * Dd + c0 + tx];
    __syncthreads();
    #pragma unroll
    for (int j = 0; j < 4; ++j)
      WinT[(size_t)(c0 + ty + j*8) * Ee + r0 + tx] = f2bf(tile[tx][ty + j*8]);
  } else {
    int gid  = (bid - 4224) * 4 + (tid >> 6);   // k*1024 + d
    int lane = tid & 63;
    int d = gid & 1023, k = gid >> 10;
    const float* wrow = Wout + (size_t)d * Ee + k * Dd;
    ushort*      wbf  = Wout_bf + (size_t)d * Ee + k * Dd;
    const float* bv   = b_in + k * Dd;
    float sc = 0.f, sz0 = 0.f, sz1 = 0.f, sz2 = 0.f, sz3 = 0.f;
    #pragma unroll
    for (int j = 0; j < 4; ++j){
      int base = lane*4 + j*256;
      float4 wv = *(const float4*)(wrow + base);
      ushort4 ob; ob.x = f2bf(wv.x); ob.y = f2bf(wv.y); ob.z = f2bf(wv.z); ob.w = f2bf(wv.w);
      *(ushort4*)(wbf + base) = ob;
      float4 bb4 = *(const float4*)(bv + base);
      sc += wv.x*bb4.x + wv.y*bb4.y + wv.z*bb4.z + wv.w*bb4.w;
      #pragma unroll
      for (int b = 0; b < 4; ++b){
        const float* sv = s0 + ((size_t)(b*Kk + k) << 10) + base;
        float4 s4 = *(const float4*)sv;
        float acc = wv.x*s4.x + wv.y*s4.y + wv.z*s4.z + wv.w*s4.w;
        if (b == 0) sz0 += acc; else if (b == 1) sz1 += acc;
        else if (b == 2) sz2 += acc; else sz3 += acc;
      }
    }
    for (int off = 32; off; off >>= 1){
      sc  += __shfl_down(sc, off);
      sz0 += __shfl_down(sz0, off);
      sz1 += __shfl_down(sz1, off);
      sz2 += __shfl_down(sz2, off);
      sz3 += __shfl_down(sz3, off);
    }
    if (lane == 0){
      cterm[gid] = sc;
      z0[gid]          = sz0;     // layout [b][k*1024+d], b stride 4096
      z0[gid + 4096]   = sz1;
      z0[gid + 8192]   = sz2;
      z0[gid + 12288]  = sz3;
    }
  }
}

// ---------------- mid: zeta cross-chunk incomings + vfull -------------------
__global__ __launch_bounds__(256) void k_mid(const float* __restrict__ vpart,
                                             const float* __restrict__ dlog,
                                             float* __restrict__ incoming,
                                             float* __restrict__ vfull){
  int idx = blockIdx.x * 256 + threadIdx.x;   // 16384: (b,k,d)
  int k = (idx >> 10) & 3, b = idx >> 12, d = idx & 1023;
  float p  = sigm(dlog[k]);
  float dL = powf(p, (float)LCH);
  float inc = 0.f;                 // zeta is a pure-u scan (init 0)
  for (int c = 0; c < NCH; ++c){
    size_t o = (((size_t)(b*NCH + c)) * Kk + k) * Dd + d;
    incoming[o] = inc;
    inc = dL * inc + vpart[o];
  }
  vfull[idx] = inc;
}

// ---------------- zeta apply: u -> zeta_bf (B,T,K,D) ------------------------
__global__ __launch_bounds__(256) void k_zeta(const float* __restrict__ u,
                                              const float* __restrict__ incoming,
                                              const float* __restrict__ dlog,
                                              ushort* __restrict__ zeta){
  int x = blockIdx.x;             // b*NCH + c
  int k = blockIdx.y;
  int c = x & 31, b = x >> 5;
  int d0 = threadIdx.x * 4;
  float p = sigm(dlog[k]);
  f32x4 z = *(const f32x4*)&incoming[(((size_t)x) * Kk + k) * Dd + d0];
  size_t ub = ((size_t)(b*Tt + c*LCH)) * Dd + d0;
  size_t zb = ((size_t)(b*Tt + c*LCH)) * Ee + k*Dd + d0;
  for (int i = 0; i < LCH; ++i){
    f32x4 uv = *(const f32x4*)(u + ub);
    z = p*z + uv;
    ushort4 o; o.x = f2bf(z[0]); o.y = f2bf(z[1]); o.z = f2bf(z[2]); o.w = f2bf(z[3]);
    *(ushort4*)(zeta + zb) = o;
    ub += Dd; zb += Ee;
  }
}

// ---------------- small NT GEMM for Mcat3[d, k*1024+d'] ---------------------
__global__ __launch_bounds__(256) void gemm_nt(const ushort* __restrict__ A,
                                               const ushort* __restrict__ B,
                                               ushort* __restrict__ C,
                                               int Kred, int lda, int ldb, int ldc,
                                               long aBatch, long bBatch, long cBatch){
  __shared__ ushort As[128 * 32];
  __shared__ ushort Bs[128 * 32];
  A += (long)blockIdx.z * aBatch;
  B += (long)blockIdx.z * bBatch;
  C += (long)blockIdx.z * cBatch;
  const int tid  = threadIdx.x;
  const int lane = tid & 63;
  const int w    = tid >> 6;
  const int wr   = w >> 1, wc = w & 1;
  const int rowBase = blockIdx.x * 128;
  const int colBase = blockIdx.y * 128;

  f32x4 acc[4][4] = {};
  const int krow = (lane >> 4) * 8;
  const int rsel = lane & 15;

  for (int kk = 0; kk < Kred; kk += 32){
    __syncthreads();
    #pragma unroll
    for (int i = 0; i < 2; ++i){
      int c  = i * 256 + tid;
      int r  = c >> 2;
      int c8 = (c & 3) * 8;
      const ushort* ga = A + (size_t)(rowBase + r) * lda + kk + c8;
      const ushort* gb = B + (size_t)(colBase + r) * ldb + kk + c8;
      __builtin_amdgcn_global_load_lds((const __attribute__((address_space(1))) void*)ga,
                                       (__attribute__((address_space(3))) void*)&As[c * 8],
                                       16, 0, 0);
      __builtin_amdgcn_global_load_lds((const __attribute__((address_space(1))) void*)gb,
                                       (__attribute__((address_space(3))) void*)&Bs[c * 8],
                                       16, 0, 0);
    }
    asm volatile("s_waitcnt vmcnt(0)" ::: "memory");
    __syncthreads();

    bf16x8 Af[4], Bf[4];
    #pragma unroll
    for (int mi = 0; mi < 4; ++mi)
      Af[mi] = *(const bf16x8*)&As[(wr*64 + mi*16 + rsel) * 32 + krow];
    #pragma unroll
    for (int ni = 0; ni < 4; ++ni)
      Bf[ni] = *(const bf16x8*)&Bs[(wc*64 + ni*16 + rsel) * 32 + krow];
    #pragma unroll
    for (int mi = 0; mi < 4; ++mi)
      #pragma unroll
      for (int ni = 0; ni < 4; ++ni)
        acc[mi][ni] = __builtin_amdgcn_mfma_f32_16x16x32_bf16(Af[mi], Bf[ni], acc[mi][ni], 0, 0, 0);
  }

  #pragma unroll
  for (int mi = 0; mi < 4; ++mi){
    #pragma unroll
    for (int ni = 0; ni < 4; ++ni){
      int r0 = rowBase + wr*64 + mi*16 + (lane >> 4) * 4;
      int c0 = colBase + wc*64 + ni*16 + (lane & 15);
      #pragma unroll
      for (int q = 0; q < 4; ++q)
        C[(size_t)(r0 + q) * ldc + c0] = f2bf(acc[mi][ni][q]);
    }
  }
}

// ---------------- big GEMM: g[8192,1024] = zeta[8192,4096] @ Mcat3^T --------
// 128x128, 4 waves, BK=32, K=4096 (128 iters). Operand stride 4096.
#define STAGE_OP(GB, LOFF)                                                     \
  { _Pragma("unroll")                                                          \
    for (int i_ = 0; i_ < 2; ++i_){                                            \
      int c_ = tid + i_*256;                                                   \
      int row_ = c_ >> 2;                                                      \
      int ss_ = (c_ & 3) ^ ((row_ >> 1) & 3);                                  \
      const ushort* g_ = (GB) + (size_t)row_ * 4096 + ss_ * 8;                 \
      __builtin_amdgcn_global_load_lds(                                        \
        (const __attribute__((address_space(1))) void*)g_,                     \
        (__attribute__((address_space(3))) void*)&lds[(LOFF) + c_*8],          \
        16, 0, 0);                                                             \
    } }

#define LOAD_A4(DST)                                                           \
  { _Pragma("unroll")                                                          \
    for (int mi_ = 0; mi_ < 4; ++mi_){                                         \
      int r_ = wm*64 + mi_*16 + rsel;                                          \
      int uo_ = r_*32 + kq*8;                                                  \
      uo_ ^= ((uo_ >> 6) & 3) << 3;                                            \
      DST[mi_] = *(const bf16x8*)&lds[cbase + uo_];                            \
    } }

#define LOAD_B4(DST)                                                           \
  { _Pragma("unroll")                                                          \
    for (int ni_ = 0; ni_ < 4; ++ni_){                                         \
      int r_ = wn*64 + ni_*16 + rsel;                                          \
      int uo_ = r_*32 + kq*8;                                                  \
      uo_ ^= ((uo_ >> 6) & 3) << 3;                                            \
      DST[ni_] = *(const bf16x8*)&lds[cbase + 4096 + uo_];                     \
    } }

#define BAR() __builtin_amdgcn_s_barrier()

__global__ __launch_bounds__(256, 4) void gemm_big(const ushort* __restrict__ A,
                                                   const ushort* __restrict__ B,
                                                   float* __restrict__ g,
                                                   const float* __restrict__ dlog,
                                                   const float* __restrict__ z0,
                                                   const float* __restrict__ cterm,
                                                   const float* __restrict__ b_out){
  __shared__ ushort lds[16384];       // 32 KB
  const int tid  = threadIdx.x;
  const int lane = tid & 63;
  const int w    = tid >> 6;          // 0..3
  const int wm   = w >> 1;
  const int wn   = w & 1;
  const int rsel = lane & 15;
  const int kq   = lane >> 4;

  // XCD map: grid 512 = 64M x 8N tiles; each XCD owns 8Mx8N.
  int bid = blockIdx.x;
  int xcd = bid & 7, rr = bid >> 3;   // rr 0..63
  const int rowBase = (xcd * 8 + (rr & 7)) * 128;   // 64 M-tiles (bt)
  const int colBase = (rr >> 3) * 128;              // 8 N-tiles (d_out)

  const ushort* Ag = A + (size_t)rowBase * 4096;
  const ushort* Bg = B + (size_t)colBase * 4096;

  f32x4 acc[4][4] = {};

  STAGE_OP(Ag +  0, 0);
  STAGE_OP(Bg +  0, 4096);
  STAGE_OP(Ag + 32, 8192);
  STAGE_OP(Bg + 32, 8192 + 4096);
  asm volatile("s_waitcnt vmcnt(4)" ::: "memory");
  BAR();

  for (int t = 0; t < 128; ++t){
    const int cbase = (t & 1) * 8192;
    bf16x8 af[4], bf[4];
    LOAD_A4(af); LOAD_B4(bf);
    #pragma unroll
    for (int mi = 0; mi < 4; ++mi)
      #pragma unroll
      for (int ni = 0; ni < 4; ++ni)
        acc[mi][ni] = __builtin_amdgcn_mfma_f32_16x16x32_bf16(af[mi], bf[ni], acc[mi][ni], 0, 0, 0);
    asm volatile("s_waitcnt lgkmcnt(0)" ::: "memory");
    BAR();
    if (t < 126){
      STAGE_OP(Ag + (t+2)*32, cbase);
      STAGE_OP(Bg + (t+2)*32, cbase + 4096);
      asm volatile("s_waitcnt vmcnt(4)" ::: "memory");
    } else {
      asm volatile("s_waitcnt vmcnt(0)" ::: "memory");
    }
    BAR();
  }

  // ---- epilogue: g = acc + b_out + sum_k [pw*z0 + ct*(1-pw)], pw=p^{t+1}
  {
    const int b  = rowBase >> 11;
    const int t0 = rowBase & 2047;
    const int c0 = colBase + wn*64 + rsel;     // col for j=0 (+j*16)
    float boj[4], ctsum[4], d0v[4][4];
    #pragma unroll
    for (int j = 0; j < 4; ++j){
      int cj = c0 + j*16;
      boj[j] = b_out[cj];
      float cs = 0.f;
      #pragma unroll
      for (int k = 0; k < 4; ++k){
        float p   = sigm(dlog[k]);
        float omp = fmaxf(1.0f - p, 1e-30f);
        float ct  = cterm[k*Dd + cj] / omp;
        d0v[k][j] = z0[b*4096 + k*Dd + cj] - ct;
        cs += ct;
      }
      ctsum[j] = cs;
    }
    float pk[4], p16[4], pwm[4];
    int tfirst = t0 + wm*64 + (lane >> 4)*4;
    #pragma unroll
    for (int k = 0; k < 4; ++k){
      pk[k]  = sigm(dlog[k]);
      pwm[k] = powf(pk[k], (float)(tfirst + 1));
      p16[k] = powf(pk[k], 16.0f);
    }
    #pragma unroll
    for (int mi = 0; mi < 4; ++mi){
      float pwr[4];
      #pragma unroll
      for (int k = 0; k < 4; ++k) pwr[k] = pwm[k];
      #pragma unroll
      for (int q = 0; q < 4; ++q){
        int r = rowBase + wm*64 + mi*16 + (lane >> 4)*4 + q;
        #pragma unroll
        for (int j = 0; j < 4; ++j){
          float gg = acc[mi][j][q] + boj[j] + ctsum[j];
          #pragma unroll
          for (int k = 0; k < 4; ++k) gg += pwr[k] * d0v[k][j];
          g[(size_t)r * Dd + c0 + j*16] = gg;
        }
        #pragma unroll
        for (int k = 0; k < 4; ++k) pwr[k] *= pk[k];
      }
      #pragma unroll
      for (int k = 0; k < 4; ++k) pwm[k] *= p16[k];
    }
  }
}

// ---------------- slast: wave per (b,k,d) -----------------------------------
__global__ __launch_bounds__(256) void k_slast(const float* __restrict__ W_in,
                                               const float* __restrict__ vfull,
                                               const float* __restrict__ s0,
                                               const float* __restrict__ b_in,
                                               const float* __restrict__ dlog,
                                               float* __restrict__ out){
  int gid  = blockIdx.x * 4 + (threadIdx.x >> 6);
  int lane = threadIdx.x & 63;
  int d = gid & 1023, k = (gid >> 10) & 3, b = gid >> 12;
  const float* wrow = W_in + (size_t)(k*Dd + d) * Dd;
  const float* vv   = vfull + ((size_t)(b*Kk + k) << 10);
  float s = 0.f;
  #pragma unroll
  for (int j = 0; j < 4; ++j){
    int base = lane*4 + j*256;
    float4 w4 = *(const float4*)(wrow + base);
    float4 v4 = *(const float4*)(vv + base);
    s += w4.x*v4.x + w4.y*v4.y + w4.z*v4.z + w4.w*v4.w;
  }
  for (int off = 32; off; off >>= 1) s += __shfl_down(s, off);
  if (lane == 0){
    float p  = sigm(dlog[k]);
    float pT = powf(p, (float)Tt);
    float omp = 1.0f - p;
    float geo = (omp < 1e-12f) ? (float)Tt : (1.0f - pT) / omp;
    out[gid] = pT * s0[gid] + s + b_in[k*Dd + d] * geo;
  }
}

// ---------------------------------------------------------------------------
extern "C" void kernel_launch(void* const* d_in, const int* in_sizes, int n_in,
                              void* d_out, int out_size, void* d_ws, size_t ws_size,
                              hipStream_t stream){
  const float* u     = (const float*)d_in[0];
  const float* s0    = (const float*)d_in[1];
  const float* W_in  = (const float*)d_in[2];
  const float* b_in  = (const float*)d_in[3];
  const float* W_out = (const float*)d_in[4];
  const float* b_out = (const float*)d_in[5];
  const float* dlog  = (const float*)d_in[6];

  float* g_out     = (float*)d_out;                      // B*T*D
  float* slast_out = g_out + (size_t)BT * Dd;            // B*K*D

  char* ws = (char*)d_ws;
  if (ws_size < 115490816ull) return;
  ushort* WinT    = (ushort*)(ws + 16777216);            //  8 MB
  ushort* Wout_bf = (ushort*)(ws + 25165824);            //  8 MB
  ushort* Mcat3   = (ushort*)(ws + 33554432);            //  8 MB
  ushort* zeta    = (ushort*)(ws + 41943040);            // 64 MB
  float*  incoming= (float*)(ws + 111149056);            //  2 MB
  float*  z0buf   = (float*)(ws + 113246208);            // 64 KB
  float*  cterm   = (float*)(ws + 113311744);            // 16 KB
  float*  vpart   = (float*)(ws + 113328128);            //  2 MB
  float*  vfull   = (float*)(ws + 115425280);            // 64 KB

  // 1) fused prep: u-carries | W_in transpose | W_out (bf16 + z0 + cterm)
  k_prep_all<<<5248, 256, 0, stream>>>(u, dlog, vpart,
                                       W_in, WinT,
                                       W_out, s0, b_in, Wout_bf, z0buf, cterm);

  // 2) zeta cross-chunk incomings + vfull
  k_mid<<<64, 256, 0, stream>>>(vpart, dlog, incoming, vfull);

  // 3) zeta apply: u -> zeta_bf (B,T,K,D)
  k_zeta<<<dim3(128, 4), 256, 0, stream>>>(u, incoming, dlog, zeta);

  // 4) Mcat3[d, k*1024+d'] = sum_j Wout[d,kD+j] Win[kD+j,d']
  gemm_nt<<<dim3(8, 8, 4), 256, 0, stream>>>(Wout_bf, WinT, Mcat3,
                                             1024, Ee, Ee, Ee,
                                             1024L, 1024L, 1024L);

  // 5) g = zeta @ Mcat3^T + epilogue terms (writes f32 g directly)
  gemm_big<<<512, 256, 0, stream>>>(zeta, Mcat3, g_out, dlog,
                                    z0buf, cterm, b_out);

  // 6) s_last
  k_slast<<<4096, 256, 0, stream>>>(W_in, vfull, s0, b_in, dlog, slast_out);
}